// Round 2
// baseline (1463.492 us; speedup 1.0000x reference)
//
#include <hip/hip_runtime.h>
#include <math.h>

#define BB 4
#define LSEQ 2048
#define DMODEL 128
#define DINNER 256
#define DSTATE 16
#define DTRANK 8
#define NLAYERS 8
#define NCH 128    // number of time chunks
#define LCH 16     // chunk length (LSEQ / NCH)

__device__ __forceinline__ float silu_f(float x) {
    return x / (1.0f + __expf(-x));
}

__device__ __forceinline__ float softplus_f(float x) {
    return (x > 20.0f) ? x : log1pf(__expf(x));
}

// ---------------- stem: h[b,l,m] = sum_s x[b, l*4+s] * sw[m,s] + sb[m] ----
__global__ __launch_bounds__(256)
void k_stem(const float* __restrict__ x, const float* __restrict__ sw,
            const float* __restrict__ sb, float* __restrict__ h)
{
    int i = blockIdx.x * 256 + threadIdx.x;
    if (i >= BB * LSEQ * DMODEL) return;
    int m = i & (DMODEL - 1);
    int bl = i >> 7;
    const float* xf = x + bl * 4;
    float4 w = *(const float4*)(sw + m * 4);
    h[i] = sb[m] + xf[0]*w.x + xf[1]*w.y + xf[2]*w.z + xf[3]*w.w;
}

// ---------------- K_A: LayerNorm + in_proj (512 outputs) ------------------
// 16 positions/block. Proj phase: thread = (p = t&15, og = t>>4); og owns 32
// consecutive output rows; the 16 lanes sharing og read the SAME weight
// address (broadcast, 4 lines/wave-instr instead of 64).
__global__ __launch_bounds__(256)
void k_ln_inproj(const float* __restrict__ h, const float* __restrict__ g,
                 const float* __restrict__ bln, const float* __restrict__ W,
                 float* __restrict__ xp_pre, float* __restrict__ z)
{
    __shared__ float xn[16][132];
    int pos0 = blockIdx.x * 16;
    int t = threadIdx.x;
    for (int j = t; j < 16 * DMODEL; j += 256)
        xn[j >> 7][j & 127] = h[pos0 * DMODEL + j];
    __syncthreads();
    {
        int r = t >> 4, lane = t & 15;
        float s = 0.f;
        #pragma unroll
        for (int k = lane; k < DMODEL; k += 16) s += xn[r][k];
        #pragma unroll
        for (int off = 8; off > 0; off >>= 1) s += __shfl_xor(s, off, 16);
        float mu = s * (1.f / DMODEL);
        float vs = 0.f;
        #pragma unroll
        for (int k = lane; k < DMODEL; k += 16) { float dv = xn[r][k] - mu; vs += dv * dv; }
        #pragma unroll
        for (int off = 8; off > 0; off >>= 1) vs += __shfl_xor(vs, off, 16);
        float rstd = rsqrtf(vs * (1.f / DMODEL) + 1e-5f);
        #pragma unroll
        for (int k = lane; k < DMODEL; k += 16)
            xn[r][k] = (xn[r][k] - mu) * rstd * g[k] + bln[k];
    }
    __syncthreads();
    int p = t & 15, og = t >> 4;          // og in 0..15, outs og*32..og*32+31
    float acc[32];
    #pragma unroll
    for (int j = 0; j < 32; j++) acc[j] = 0.f;
    const float* wb = W + (size_t)og * 32 * DMODEL;
    for (int k4 = 0; k4 < DMODEL / 4; k4++) {
        float4 xv = *(const float4*)&xn[p][k4 * 4];
        #pragma unroll
        for (int j = 0; j < 32; j++) {
            float4 wv = *(const float4*)(wb + j * DMODEL + k4 * 4);
            acc[j] += wv.x*xv.x + wv.y*xv.y + wv.z*xv.z + wv.w*xv.w;
        }
    }
    float* dst = (og < 8) ? (xp_pre + (size_t)(pos0 + p) * DINNER + og * 32)
                          : (z      + (size_t)(pos0 + p) * DINNER + (og - 8) * 32);
    #pragma unroll
    for (int j4 = 0; j4 < 8; j4++)
        *(float4*)(dst + j4 * 4) = make_float4(acc[j4*4], acc[j4*4+1], acc[j4*4+2], acc[j4*4+3]);
}

// ---------------- K_B: conv+SiLU+x_proj+dt+softplus+local chunk scan ------
// grid (NCH, BB). Block = 16 positions x 256 channels.
__global__ __launch_bounds__(256)
void k_fusedB(const float* __restrict__ xp_pre, const float* __restrict__ cw,
              const float* __restrict__ cb, const float* __restrict__ xw,
              const float* __restrict__ dw, const float* __restrict__ db,
              const float* __restrict__ A_log, const float* __restrict__ Dv,
              float* __restrict__ delta_out, float* __restrict__ Cm_out,
              float* __restrict__ y, float* __restrict__ P, float* __restrict__ hF)
{
    __shared__ float pre[LCH + 3][260];   // rows = positions t0-3 .. t0+15
    __shared__ float dbl[LCH][40];        // x_proj outputs: 0..7 dt, 8..23 B, 24..39 C
    int c = blockIdx.x, b = blockIdx.y;
    int t0 = c * LCH;
    int pos0 = b * LSEQ + t0;
    int t = threadIdx.x;
    for (int j = t; j < (LCH + 3) * DINNER; j += 256) {
        int r = j >> 8, d = j & 255;
        int l = t0 + r - 3;
        pre[r][d] = (l < 0) ? 0.f : xp_pre[(size_t)(b * LSEQ + l) * DINNER + d];
    }
    __syncthreads();
    {   // conv + silu, in place (column-private: thread t = channel d)
        int d = t;
        float4 cwv = *(const float4*)(cw + d * 4);
        float cbv = cb[d];
        float p0 = pre[0][d], p1 = pre[1][d], p2 = pre[2][d];
        #pragma unroll
        for (int p = 0; p < LCH; p++) {
            float cur = pre[p + 3][d];
            float xc = cbv + p0*cwv.x + p1*cwv.y + p2*cwv.z + cur*cwv.w;
            pre[p][d] = silu_f(xc);      // xs[p] stored at row p
            p0 = p1; p1 = p2; p2 = cur;
        }
    }
    __syncthreads();
    {   // x_proj: outs 0..31 by all threads (2 each), outs 32..39 by wave 0
        int p = t & 15, og = t >> 4;
        float a0 = 0.f, a1 = 0.f;
        const float* w0 = xw + (og * 2) * DINNER;
        const float* w1 = xw + (og * 2 + 1) * DINNER;
        for (int k4 = 0; k4 < DINNER / 4; k4++) {
            float4 xv = *(const float4*)&pre[p][k4 * 4];
            float4 wa = *(const float4*)(w0 + k4 * 4);
            float4 wb2 = *(const float4*)(w1 + k4 * 4);
            a0 += wa.x*xv.x + wa.y*xv.y + wa.z*xv.z + wa.w*xv.w;
            a1 += wb2.x*xv.x + wb2.y*xv.y + wb2.z*xv.z + wb2.w*xv.w;
        }
        dbl[p][og * 2] = a0;
        dbl[p][og * 2 + 1] = a1;
        if (t < 64) {
            int og2 = t >> 4;             // outs 32 + og2*2, 33 + og2*2
            float b0 = 0.f, b1 = 0.f;
            const float* v0 = xw + (32 + og2 * 2) * DINNER;
            const float* v1 = xw + (33 + og2 * 2) * DINNER;
            for (int k4 = 0; k4 < DINNER / 4; k4++) {
                float4 xv = *(const float4*)&pre[p][k4 * 4];
                float4 wa = *(const float4*)(v0 + k4 * 4);
                float4 wb2 = *(const float4*)(v1 + k4 * 4);
                b0 += wa.x*xv.x + wa.y*xv.y + wa.z*xv.z + wa.w*xv.w;
                b1 += wb2.x*xv.x + wb2.y*xv.y + wb2.z*xv.z + wb2.w*xv.w;
            }
            dbl[p][32 + og2 * 2] = b0;
            dbl[p][33 + og2 * 2] = b1;
        }
    }
    __syncthreads();
    {   // dt_proj + softplus + local scan; thread = channel d
        int d = t;
        float4 dw0 = *(const float4*)(dw + d * 8);
        float4 dw1 = *(const float4*)(dw + d * 8 + 4);
        float dbv = db[d];
        float dreg[LCH];
        #pragma unroll
        for (int p = 0; p < LCH; p++) {
            float v = dbv
                + dbl[p][0]*dw0.x + dbl[p][1]*dw0.y + dbl[p][2]*dw0.z + dbl[p][3]*dw0.w
                + dbl[p][4]*dw1.x + dbl[p][5]*dw1.y + dbl[p][6]*dw1.z + dbl[p][7]*dw1.w;
            dreg[p] = softplus_f(v);
            delta_out[(size_t)(pos0 + p) * DINNER + d] = dreg[p];
        }
        float Ar[DSTATE];
        #pragma unroll
        for (int n = 0; n < DSTATE; n++) Ar[n] = -__expf(A_log[d * DSTATE + n]);
        float Dd = Dv[d];
        float hs[DSTATE], S[DSTATE];
        #pragma unroll
        for (int n = 0; n < DSTATE; n++) { hs[n] = 0.f; S[n] = 0.f; }
        for (int tt = 0; tt < LCH; tt++) {
            float dlt = dreg[tt];
            float uu  = pre[tt][d];
            float du  = dlt * uu;
            float acc = uu * Dd;
            #pragma unroll
            for (int n = 0; n < DSTATE; n++) {
                float xx = dlt * Ar[n];
                S[n] += xx;
                float a = __expf(xx);
                hs[n] = fmaf(a, hs[n], du * dbl[tt][8 + n]);
                acc = fmaf(hs[n], dbl[tt][24 + n], acc);
            }
            y[(size_t)(pos0 + tt) * DINNER + d] = acc;
        }
        float* Pp = P  + ((size_t)(b * NCH + c) * DINNER + d) * DSTATE;
        float* hp = hF + ((size_t)(b * NCH + c) * DINNER + d) * DSTATE;
        #pragma unroll
        for (int n = 0; n < DSTATE; n++) { Pp[n] = __expf(S[n]); hp[n] = hs[n]; }
    }
    if (t < LCH * DSTATE) {
        int p = t >> 4, n = t & 15;
        Cm_out[(size_t)(pos0 + p) * DSTATE + n] = dbl[p][24 + n];
    }
}

// ---------------- K4: sequential combine over chunks ----------------------
__global__ __launch_bounds__(256)
void k_scanB(const float* __restrict__ P, const float* __restrict__ hF,
             float* __restrict__ hin)
{
    int idx = blockIdx.x * 256 + threadIdx.x;
    if (idx >= BB * DINNER * DSTATE) return;
    int b = idx >> 12;                 // DINNER*DSTATE = 4096
    int rem = idx & 4095;
    const float* Pp = P + (size_t)b * NCH * 4096 + rem;
    const float* hp = hF + (size_t)b * NCH * 4096 + rem;
    float* hi = hin + (size_t)b * NCH * 4096 + rem;
    float hcur = 0.f;
    #pragma unroll 4
    for (int c = 0; c < NCH; c++) {
        hi[(size_t)c * 4096] = hcur;
        hcur = Pp[(size_t)c * 4096] * hcur + hp[(size_t)c * 4096];
    }
}

// ---------------- K_C: correction + gate + out_proj + residual ------------
__global__ __launch_bounds__(256)
void k_scanC_out(const float* __restrict__ delta, const float* __restrict__ Cm,
                 const float* __restrict__ A_log, const float* __restrict__ hin,
                 const float* __restrict__ y, const float* __restrict__ z,
                 const float* __restrict__ Wout, float* __restrict__ h)
{
    __shared__ float Cs[LCH][DSTATE];
    __shared__ float yg[LCH][260];
    int c = blockIdx.x, b = blockIdx.y;
    int t0 = c * LCH;
    int pos0 = b * LSEQ + t0;
    int t = threadIdx.x;
    if (t < LCH * DSTATE) {
        int p = t >> 4, n = t & 15;
        Cs[p][n] = Cm[(size_t)(pos0 + p) * DSTATE + n];
    }
    __syncthreads();
    {   // correction + gate; thread = channel d
        int d = t;
        float Ar[DSTATE], w[DSTATE];
        #pragma unroll
        for (int n = 0; n < DSTATE; n++) Ar[n] = -__expf(A_log[d * DSTATE + n]);
        const float* hp = hin + ((size_t)(b * NCH + c) * DINNER + d) * DSTATE;
        #pragma unroll
        for (int n = 0; n < DSTATE; n++) w[n] = hp[n];
        for (int tt = 0; tt < LCH; tt++) {
            float dlt = delta[(size_t)(pos0 + tt) * DINNER + d];
            float corr = 0.f;
            #pragma unroll
            for (int n = 0; n < DSTATE; n++) {
                w[n] *= __expf(dlt * Ar[n]);
                corr = fmaf(w[n], Cs[tt][n], corr);
            }
            float yv = y[(size_t)(pos0 + tt) * DINNER + d] + corr;
            float zv = z[(size_t)(pos0 + tt) * DINNER + d];
            yg[tt][d] = yv * silu_f(zv);
        }
    }
    __syncthreads();
    {   // out_proj: thread = (p = t&15, og = t>>4); og owns 8 output rows
        int p = t & 15, og = t >> 4;
        float acc[8];
        #pragma unroll
        for (int j = 0; j < 8; j++) acc[j] = 0.f;
        const float* wb = Wout + (size_t)og * 8 * DINNER;
        for (int k4 = 0; k4 < DINNER / 4; k4++) {
            float4 xv = *(const float4*)&yg[p][k4 * 4];
            #pragma unroll
            for (int j = 0; j < 8; j++) {
                float4 wv = *(const float4*)(wb + j * DINNER + k4 * 4);
                acc[j] += wv.x*xv.x + wv.y*xv.y + wv.z*xv.z + wv.w*xv.w;
            }
        }
        float* hrow = h + (size_t)(pos0 + p) * DMODEL + og * 8;
        float4 h0 = *(float4*)(hrow);
        float4 h1 = *(float4*)(hrow + 4);
        h0.x += acc[0]; h0.y += acc[1]; h0.z += acc[2]; h0.w += acc[3];
        h1.x += acc[4]; h1.y += acc[5]; h1.z += acc[6]; h1.w += acc[7];
        *(float4*)(hrow) = h0;
        *(float4*)(hrow + 4) = h1;
    }
}

// ---------------- head: mean-pool + classifier ---------------------------
__global__ __launch_bounds__(256)
void k_head(const float* __restrict__ h, const float* __restrict__ hw,
            const float* __restrict__ hb, float* __restrict__ out)
{
    __shared__ float part[256];
    __shared__ float pool[DMODEL];
    int b = blockIdx.x;
    int t = threadIdx.x;
    int m = t & 127, half = t >> 7;
    float s = 0.f;
    const float* hp = h + (size_t)(b * LSEQ + half * (LSEQ / 2)) * DMODEL + m;
    for (int l = 0; l < LSEQ / 2; l++) s += hp[l * DMODEL];
    part[t] = s;
    __syncthreads();
    if (t < DMODEL) pool[t] = (part[t] + part[t + 128]) * (1.f / LSEQ);
    __syncthreads();
    if (t < 35) {
        const float* wr = hw + t * DMODEL;
        float acc = hb[t];
        for (int k = 0; k < DMODEL; k++) acc += pool[k] * wr[k];
        out[b * 35 + t] = acc;
    }
}

extern "C" void kernel_launch(void* const* d_in, const int* in_sizes, int n_in,
                              void* d_out, int out_size, void* d_ws, size_t ws_size,
                              hipStream_t stream)
{
    const float* x       = (const float*)d_in[0];
    const float* stem_w  = (const float*)d_in[1];
    const float* stem_b  = (const float*)d_in[2];
    const float* ln_g    = (const float*)d_in[3];
    const float* ln_b    = (const float*)d_in[4];
    const float* in_w    = (const float*)d_in[5];
    const float* conv_w  = (const float*)d_in[6];
    const float* conv_b  = (const float*)d_in[7];
    const float* xw      = (const float*)d_in[8];
    const float* dt_w    = (const float*)d_in[9];
    const float* dt_b    = (const float*)d_in[10];
    const float* A_log   = (const float*)d_in[11];
    const float* Dv      = (const float*)d_in[12];
    const float* out_w   = (const float*)d_in[13];
    const float* head_w  = (const float*)d_in[14];
    const float* head_b  = (const float*)d_in[15];
    float* out = (float*)d_out;

    float* ws     = (float*)d_ws;
    float* h      = ws;
    float* xp_pre = h      + (size_t)BB * LSEQ * DMODEL;
    float* zbuf   = xp_pre + (size_t)BB * LSEQ * DINNER;
    float* dbuf   = zbuf   + (size_t)BB * LSEQ * DINNER;
    float* Cmb    = dbuf   + (size_t)BB * LSEQ * DINNER;
    float* ybuf   = Cmb    + (size_t)BB * LSEQ * DSTATE;
    float* Pb     = ybuf   + (size_t)BB * LSEQ * DINNER;
    float* hFb    = Pb     + (size_t)BB * NCH * DINNER * DSTATE;
    float* hinb   = hFb    + (size_t)BB * NCH * DINNER * DSTATE;

    k_stem<<<(BB * LSEQ * DMODEL + 255) / 256, 256, 0, stream>>>(x, stem_w, stem_b, h);

    dim3 gs(NCH, BB);
    for (int ly = 0; ly < NLAYERS; ly++) {
        k_ln_inproj<<<BB * LSEQ / 16, 256, 0, stream>>>(
            h, ln_g + ly * DMODEL, ln_b + ly * DMODEL,
            in_w + (size_t)ly * 2 * DINNER * DMODEL, xp_pre, zbuf);
        k_fusedB<<<gs, 256, 0, stream>>>(
            xp_pre, conv_w + (size_t)ly * DINNER * 4, conv_b + (size_t)ly * DINNER,
            xw + (size_t)ly * 40 * DINNER, dt_w + (size_t)ly * DINNER * DTRANK,
            dt_b + (size_t)ly * DINNER, A_log + (size_t)ly * DINNER * DSTATE,
            Dv + (size_t)ly * DINNER, dbuf, Cmb, ybuf, Pb, hFb);
        k_scanB<<<(BB * DINNER * DSTATE + 255) / 256, 256, 0, stream>>>(Pb, hFb, hinb);
        k_scanC_out<<<gs, 256, 0, stream>>>(
            dbuf, Cmb, A_log + (size_t)ly * DINNER * DSTATE, hinb,
            ybuf, zbuf, out_w + (size_t)ly * DMODEL * DINNER, h);
    }
    k_head<<<BB, 256, 0, stream>>>(h, head_w, head_b, out);
}

// Round 3
// 1075.242 us; speedup vs baseline: 1.3611x; 1.3611x over previous
//
#include <hip/hip_runtime.h>
#include <math.h>

#define BB 4
#define LSEQ 2048
#define DMODEL 128
#define DINNER 256
#define DSTATE 16
#define NLAYERS 8
#define NCH 128    // number of time chunks
#define LCH 16     // chunk length
#define HALO 3
#define ROWS (LCH + HALO)   // 19

__device__ __forceinline__ float silu_f(float x) {
    return x / (1.0f + __expf(-x));
}
__device__ __forceinline__ float softplus_f(float x) {
    return (x > 20.0f) ? x : log1pf(__expf(x));
}
__device__ __forceinline__ float dot4(float4 a, float4 b) {
    return a.x*b.x + a.y*b.y + a.z*b.z + a.w*b.w;
}

// ---------------- stem ----------------------------------------------------
__global__ __launch_bounds__(256)
void k_stem(const float* __restrict__ x, const float* __restrict__ sw,
            const float* __restrict__ sb, float* __restrict__ h)
{
    int i = blockIdx.x * 256 + threadIdx.x;
    if (i >= BB * LSEQ * DMODEL) return;
    int m = i & (DMODEL - 1);
    int bl = i >> 7;
    const float* xf = x + bl * 4;
    float4 w = *(const float4*)(sw + m * 4);
    h[i] = sb[m] + xf[0]*w.x + xf[1]*w.y + xf[2]*w.z + xf[3]*w.w;
}

// ---------------- K_A: LN+in_proj+conv+silu+x_proj+dt+softplus+local scan -
// grid (NCH, BB), 256 threads.
__global__ __launch_bounds__(256, 2)
void k_layer_a(const float* __restrict__ h, const float* __restrict__ g,
               const float* __restrict__ bln, const float* __restrict__ W,
               const float* __restrict__ cw, const float* __restrict__ cb,
               const float* __restrict__ xw, const float* __restrict__ dw,
               const float* __restrict__ db, const float* __restrict__ A_log,
               const float* __restrict__ Dv,
               float* __restrict__ z, float* __restrict__ delta_out,
               float* __restrict__ Cm, float* __restrict__ y,
               float* __restrict__ P, float* __restrict__ hF)
{
    __shared__ float xn[ROWS][132];    // normalized input rows (pos t0-3..t0+15)
    __shared__ float xp[ROWS][260];    // in_proj xp; rows 0..15 become xs after conv
    __shared__ float xwS[40][DINNER];  // x_proj weights staged
    __shared__ float dbl[LCH][40];     // x_proj outputs: 0..7 dt, 8..23 B, 24..39 C
    int c = blockIdx.x, b = blockIdx.y;
    int t0 = c * LCH;
    int pos0 = b * LSEQ + t0;
    int t = threadIdx.x;

    // stage input rows (halo rows with l<0 are zero) + x_proj weights
    for (int j = t; j < ROWS * DMODEL; j += 256) {
        int r = j >> 7, col = j & 127;
        int l = t0 - HALO + r;
        xn[r][col] = (l < 0) ? 0.f : h[(size_t)(b * LSEQ + l) * DMODEL + col];
    }
    for (int j = t; j < 40 * DINNER; j += 256)
        ((float*)xwS)[j] = xw[j];
    __syncthreads();

    // LayerNorm in place: 8 lanes per row
    {
        int r = t >> 3, lane = t & 7;
        if (r < ROWS && (t0 - HALO + r) >= 0) {
            float s = 0.f;
            #pragma unroll
            for (int k = lane; k < DMODEL; k += 8) s += xn[r][k];
            #pragma unroll
            for (int off = 4; off > 0; off >>= 1) s += __shfl_xor(s, off, 8);
            float mu = s * (1.f / DMODEL);
            float vs = 0.f;
            #pragma unroll
            for (int k = lane; k < DMODEL; k += 8) { float dv = xn[r][k] - mu; vs += dv * dv; }
            #pragma unroll
            for (int off = 4; off > 0; off >>= 1) vs += __shfl_xor(vs, off, 8);
            float rstd = rsqrtf(vs * (1.f / DMODEL) + 1e-5f);
            #pragma unroll
            for (int k = lane; k < DMODEL; k += 8)
                xn[r][k] = (xn[r][k] - mu) * rstd * g[k] + bln[k];
        }
    }
    __syncthreads();

    // in_proj: thread owns W row t (-> xp, 19 rows) and row 256+t (-> z, 16 rows)
    {
        const float4* w0 = (const float4*)(W + (size_t)t * DMODEL);
        const float4* w1 = (const float4*)(W + (size_t)(DINNER + t) * DMODEL);
        float a0[ROWS], a1[LCH];
        #pragma unroll
        for (int p = 0; p < ROWS; p++) a0[p] = 0.f;
        #pragma unroll
        for (int p = 0; p < LCH; p++) a1[p] = 0.f;
        #pragma unroll 2
        for (int k4 = 0; k4 < DMODEL / 4; k4++) {
            float4 wa = w0[k4], wb = w1[k4];
            #pragma unroll
            for (int p = 0; p < ROWS; p++) {
                float4 xv = *(const float4*)&xn[p][k4 * 4];
                a0[p] += dot4(wa, xv);
                if (p >= HALO) a1[p - HALO] += dot4(wb, xv);
            }
        }
        #pragma unroll
        for (int p = 0; p < ROWS; p++) xp[p][t] = a0[p];
        #pragma unroll
        for (int p = 0; p < LCH; p++)
            z[(size_t)(pos0 + p) * DINNER + t] = a1[p];
    }
    __syncthreads();

    // causal conv + silu, in place (column-private)
    {
        int d = t;
        float4 cwv = *(const float4*)(cw + d * 4);
        float cbv = cb[d];
        float q0 = xp[0][d], q1 = xp[1][d], q2 = xp[2][d];
        #pragma unroll
        for (int p = 0; p < LCH; p++) {
            float cur = xp[p + HALO][d];
            float xc = cbv + q0*cwv.x + q1*cwv.y + q2*cwv.z + cur*cwv.w;
            xp[p][d] = silu_f(xc);
            q0 = q1; q1 = q2; q2 = cur;
        }
    }
    __syncthreads();

    // x_proj from LDS weights: outs 0..31 by all threads (2 each), 32..39 by t<64
    {
        int p = t & 15, og = t >> 4;
        float a0 = 0.f, a1 = 0.f;
        const float* w0 = xwS[og * 2];
        const float* w1 = xwS[og * 2 + 1];
        for (int k4 = 0; k4 < DINNER / 4; k4++) {
            float4 xv = *(const float4*)&xp[p][k4 * 4];
            a0 += dot4(*(const float4*)(w0 + k4 * 4), xv);
            a1 += dot4(*(const float4*)(w1 + k4 * 4), xv);
        }
        dbl[p][og * 2] = a0;
        dbl[p][og * 2 + 1] = a1;
        if (t < 64) {
            int og2 = t >> 4;
            float b0 = 0.f, b1 = 0.f;
            const float* v0 = xwS[32 + og2 * 2];
            const float* v1 = xwS[33 + og2 * 2];
            for (int k4 = 0; k4 < DINNER / 4; k4++) {
                float4 xv = *(const float4*)&xp[p][k4 * 4];
                b0 += dot4(*(const float4*)(v0 + k4 * 4), xv);
                b1 += dot4(*(const float4*)(v1 + k4 * 4), xv);
            }
            dbl[p][32 + og2 * 2] = b0;
            dbl[p][33 + og2 * 2] = b1;
        }
    }
    __syncthreads();

    // dt_proj + softplus + local chunk scan; thread = channel d
    {
        int d = t;
        float4 dwa = *(const float4*)(dw + d * 8);
        float4 dwb = *(const float4*)(dw + d * 8 + 4);
        float dbv = db[d];
        float dreg[LCH];
        #pragma unroll
        for (int p = 0; p < LCH; p++) {
            float v = dbv
                + dbl[p][0]*dwa.x + dbl[p][1]*dwa.y + dbl[p][2]*dwa.z + dbl[p][3]*dwa.w
                + dbl[p][4]*dwb.x + dbl[p][5]*dwb.y + dbl[p][6]*dwb.z + dbl[p][7]*dwb.w;
            dreg[p] = softplus_f(v);
            delta_out[(size_t)(pos0 + p) * DINNER + d] = dreg[p];
        }
        float Ar[DSTATE];
        const float4* Alp = (const float4*)(A_log + d * DSTATE);
        #pragma unroll
        for (int n4 = 0; n4 < 4; n4++) {
            float4 av = Alp[n4];
            Ar[n4*4+0] = -__expf(av.x);
            Ar[n4*4+1] = -__expf(av.y);
            Ar[n4*4+2] = -__expf(av.z);
            Ar[n4*4+3] = -__expf(av.w);
        }
        float Dd = Dv[d];
        float hs[DSTATE], S[DSTATE];
        #pragma unroll
        for (int n = 0; n < DSTATE; n++) { hs[n] = 0.f; S[n] = 0.f; }
        for (int tt = 0; tt < LCH; tt++) {
            float dlt = dreg[tt];
            float uu  = xp[tt][d];
            float du  = dlt * uu;
            float acc = uu * Dd;
            #pragma unroll
            for (int n = 0; n < DSTATE; n++) {
                float xx = dlt * Ar[n];
                S[n] += xx;
                float a = __expf(xx);
                hs[n] = fmaf(a, hs[n], du * dbl[tt][8 + n]);
                acc = fmaf(hs[n], dbl[tt][24 + n], acc);
            }
            y[(size_t)(pos0 + tt) * DINNER + d] = acc;
        }
        float* Pp = P  + ((size_t)(b * NCH + c) * DINNER + d) * DSTATE;
        float* hp = hF + ((size_t)(b * NCH + c) * DINNER + d) * DSTATE;
        #pragma unroll
        for (int n = 0; n < DSTATE; n++) { Pp[n] = __expf(S[n]); hp[n] = hs[n]; }
    }
    // store C rows for K_C
    {
        int p = t >> 4, n = t & 15;
        Cm[(size_t)(pos0 + p) * DSTATE + n] = dbl[p][24 + n];
    }
}

// ---------------- K4: sequential combine over chunks (prefetched) ---------
__global__ __launch_bounds__(256)
void k_combine(const float* __restrict__ P, const float* __restrict__ hF,
               float* __restrict__ hin)
{
    int idx = blockIdx.x * 256 + threadIdx.x;
    if (idx >= BB * DINNER * DSTATE) return;
    int b = idx >> 12;                 // DINNER*DSTATE = 4096
    int rem = idx & 4095;
    size_t base = (size_t)b * NCH * 4096 + rem;
    const float* Pp = P + base;
    const float* hp = hF + base;
    float* hi = hin + base;
    float hcur = 0.f;
    float Pn = Pp[0], Hn = hp[0];
    for (int c = 0; c < NCH; c++) {
        hi[(size_t)c * 4096] = hcur;
        float Pc = Pn, Hc = Hn;
        if (c + 1 < NCH) {
            Pn = Pp[(size_t)(c + 1) * 4096];
            Hn = hp[(size_t)(c + 1) * 4096];
        }
        hcur = fmaf(Pc, hcur, Hc);
    }
}

// ---------------- K_C: correction + gate + out_proj + residual ------------
__global__ __launch_bounds__(256, 2)
void k_layer_c(const float* __restrict__ delta, const float* __restrict__ Cm,
               const float* __restrict__ A_log, const float* __restrict__ hin,
               const float* __restrict__ y, const float* __restrict__ z,
               const float* __restrict__ Wout, float* __restrict__ h)
{
    __shared__ float Cs[LCH][DSTATE];
    __shared__ float yg[LCH][260];
    int c = blockIdx.x, b = blockIdx.y;
    int t0 = c * LCH;
    int pos0 = b * LSEQ + t0;
    int t = threadIdx.x;
    {
        int p = t >> 4, n = t & 15;
        Cs[p][n] = Cm[(size_t)(pos0 + p) * DSTATE + n];
    }
    __syncthreads();
    {   // correction + gate; thread = channel d
        int d = t;
        float Ar[DSTATE], w[DSTATE];
        const float4* Alp = (const float4*)(A_log + d * DSTATE);
        #pragma unroll
        for (int n4 = 0; n4 < 4; n4++) {
            float4 av = Alp[n4];
            Ar[n4*4+0] = -__expf(av.x);
            Ar[n4*4+1] = -__expf(av.y);
            Ar[n4*4+2] = -__expf(av.z);
            Ar[n4*4+3] = -__expf(av.w);
        }
        const float4* hp4 = (const float4*)(hin + ((size_t)(b * NCH + c) * DINNER + d) * DSTATE);
        #pragma unroll
        for (int n4 = 0; n4 < 4; n4++) {
            float4 hv = hp4[n4];
            w[n4*4+0] = hv.x; w[n4*4+1] = hv.y; w[n4*4+2] = hv.z; w[n4*4+3] = hv.w;
        }
        for (int tt = 0; tt < LCH; tt++) {
            float dlt = delta[(size_t)(pos0 + tt) * DINNER + d];
            float corr = 0.f;
            #pragma unroll
            for (int n = 0; n < DSTATE; n++) {
                w[n] *= __expf(dlt * Ar[n]);
                corr = fmaf(w[n], Cs[tt][n], corr);
            }
            float yv = y[(size_t)(pos0 + tt) * DINNER + d] + corr;
            float zv = z[(size_t)(pos0 + tt) * DINNER + d];
            yg[tt][d] = yv * silu_f(zv);
        }
    }
    __syncthreads();
    {   // out_proj: thread owns W row m; podd splits positions by parity
        int m = t & 127, podd = t >> 7;
        float acc[8];
        #pragma unroll
        for (int i = 0; i < 8; i++) acc[i] = 0.f;
        const float4* wr = (const float4*)(Wout + (size_t)m * DINNER);
        #pragma unroll 2
        for (int k4 = 0; k4 < DINNER / 4; k4++) {
            float4 wv = wr[k4];
            #pragma unroll
            for (int i = 0; i < 8; i++) {
                float4 xv = *(const float4*)&yg[2 * i + podd][k4 * 4];
                acc[i] += dot4(wv, xv);
            }
        }
        #pragma unroll
        for (int i = 0; i < 8; i++) {
            size_t gi = (size_t)(pos0 + 2 * i + podd) * DMODEL + m;
            h[gi] += acc[i];
        }
    }
}

// ---------------- head: mean-pool + classifier ---------------------------
__global__ __launch_bounds__(256)
void k_head(const float* __restrict__ h, const float* __restrict__ hw,
            const float* __restrict__ hb, float* __restrict__ out)
{
    __shared__ float part[256];
    __shared__ float pool[DMODEL];
    int b = blockIdx.x;
    int t = threadIdx.x;
    int m = t & 127, half = t >> 7;
    float s = 0.f;
    const float* hp = h + (size_t)(b * LSEQ + half * (LSEQ / 2)) * DMODEL + m;
    for (int l = 0; l < LSEQ / 2; l++) s += hp[l * DMODEL];
    part[t] = s;
    __syncthreads();
    if (t < DMODEL) pool[t] = (part[t] + part[t + 128]) * (1.f / LSEQ);
    __syncthreads();
    if (t < 35) {
        const float* wr = hw + t * DMODEL;
        float acc = hb[t];
        for (int k = 0; k < DMODEL; k++) acc += pool[k] * wr[k];
        out[b * 35 + t] = acc;
    }
}

extern "C" void kernel_launch(void* const* d_in, const int* in_sizes, int n_in,
                              void* d_out, int out_size, void* d_ws, size_t ws_size,
                              hipStream_t stream)
{
    const float* x       = (const float*)d_in[0];
    const float* stem_w  = (const float*)d_in[1];
    const float* stem_b  = (const float*)d_in[2];
    const float* ln_g    = (const float*)d_in[3];
    const float* ln_b    = (const float*)d_in[4];
    const float* in_w    = (const float*)d_in[5];
    const float* conv_w  = (const float*)d_in[6];
    const float* conv_b  = (const float*)d_in[7];
    const float* xw      = (const float*)d_in[8];
    const float* dt_w    = (const float*)d_in[9];
    const float* dt_b    = (const float*)d_in[10];
    const float* A_log   = (const float*)d_in[11];
    const float* Dv      = (const float*)d_in[12];
    const float* out_w   = (const float*)d_in[13];
    const float* head_w  = (const float*)d_in[14];
    const float* head_b  = (const float*)d_in[15];
    float* out = (float*)d_out;

    float* ws     = (float*)d_ws;
    float* h      = ws;
    float* zbuf   = h    + (size_t)BB * LSEQ * DMODEL;
    float* dbuf   = zbuf + (size_t)BB * LSEQ * DINNER;
    float* Cmb    = dbuf + (size_t)BB * LSEQ * DINNER;
    float* ybuf   = Cmb  + (size_t)BB * LSEQ * DSTATE;
    float* Pb     = ybuf + (size_t)BB * LSEQ * DINNER;
    float* hFb    = Pb   + (size_t)BB * NCH * DINNER * DSTATE;
    float* hinb   = hFb  + (size_t)BB * NCH * DINNER * DSTATE;

    k_stem<<<(BB * LSEQ * DMODEL + 255) / 256, 256, 0, stream>>>(x, stem_w, stem_b, h);

    dim3 gs(NCH, BB);
    for (int ly = 0; ly < NLAYERS; ly++) {
        k_layer_a<<<gs, 256, 0, stream>>>(
            h, ln_g + ly * DMODEL, ln_b + ly * DMODEL,
            in_w + (size_t)ly * 2 * DINNER * DMODEL,
            conv_w + (size_t)ly * DINNER * 4, conv_b + (size_t)ly * DINNER,
            xw + (size_t)ly * 40 * DINNER, dt_w + (size_t)ly * DINNER * 8,
            dt_b + (size_t)ly * DINNER, A_log + (size_t)ly * DINNER * DSTATE,
            Dv + (size_t)ly * DINNER,
            zbuf, dbuf, Cmb, ybuf, Pb, hFb);
        k_combine<<<(BB * DINNER * DSTATE + 255) / 256, 256, 0, stream>>>(Pb, hFb, hinb);
        k_layer_c<<<gs, 256, 0, stream>>>(
            dbuf, Cmb, A_log + (size_t)ly * DINNER * DSTATE, hinb,
            ybuf, zbuf, out_w + (size_t)ly * DMODEL * DINNER, h);
    }
    k_head<<<BB, 256, 0, stream>>>(h, head_w, head_b, out);
}